// Round 1
// baseline (99.069 us; speedup 1.0000x reference)
//
#include <hip/hip_runtime.h>
#include <math.h>

// DeformationGraph: warped = sum_n skin[p,n] * (R_n (p - c_n) + t_n + c_n), skin = softmax-ish RBF
// plus edge regularizer. P=65536, N=512, E=4096. All fp32. VALU-bound.

constexpr int NP = 65536;
constexpr int NN = 512;
constexpr int NE = 4096;

__device__ __forceinline__ void rodrigues(float wx, float wy, float wz, float* R) {
    // Matches reference: theta = sqrt(w.w + 1e-12); R = I + sin(th)K + (1-cos(th))K^2
    float t2 = wx * wx + wy * wy + wz * wz + 1e-12f;
    float th = sqrtf(t2);
    float inv = 1.0f / th;
    float kx = wx * inv, ky = wy * inv, kz = wz * inv;
    float s = sinf(th);
    float c = 1.0f - cosf(th);
    float kxky = kx * ky, kxkz = kx * kz, kykz = ky * kz;
    R[0] = 1.0f - c * (ky * ky + kz * kz);
    R[1] = -s * kz + c * kxky;
    R[2] =  s * ky + c * kxkz;
    R[3] =  s * kz + c * kxky;
    R[4] = 1.0f - c * (kx * kx + kz * kz);
    R[5] = -s * kx + c * kykz;
    R[6] = -s * ky + c * kxkz;
    R[7] =  s * kx + c * kykz;
    R[8] = 1.0f - c * (kx * kx + ky * ky);
}

__global__ __launch_bounds__(256) void deform_kernel(
    const float* __restrict__ points,
    const float* __restrict__ cps,
    const float* __restrict__ rot,
    const float* __restrict__ tr,
    const int* __restrict__ edges,
    float* __restrict__ out)
{
    // Node record: [R0..R8, cx, cy, cz, cx+tx, cy+ty, cz+tz, pad] = 16 floats
    __shared__ float nd[NN * 16];
    const int bid = blockIdx.x;
    const int tid = threadIdx.x;

    if (bid < NP / 256) {
        // ---- stage node data into LDS (each block computes its own copy; ~0.7% overhead) ----
        for (int n = tid; n < NN; n += 256) {
            float R[9];
            rodrigues(rot[3 * n + 0], rot[3 * n + 1], rot[3 * n + 2], R);
            float cx = cps[3 * n + 0], cy = cps[3 * n + 1], cz = cps[3 * n + 2];
            float tx = tr[3 * n + 0], ty = tr[3 * n + 1], tz = tr[3 * n + 2];
            float* r = &nd[n * 16];
            r[0] = R[0]; r[1] = R[1]; r[2] = R[2]; r[3] = R[3];
            r[4] = R[4]; r[5] = R[5]; r[6] = R[6]; r[7] = R[7];
            r[8] = R[8]; r[9] = cx;  r[10] = cy;  r[11] = cz;
            r[12] = cx + tx; r[13] = cy + ty; r[14] = cz + tz; r[15] = 0.0f;
        }
        __syncthreads();

        // ---- one point per thread, single fused pass over all nodes ----
        const int p = bid * 256 + tid;
        const float px = points[3 * p + 0];
        const float py = points[3 * p + 1];
        const float pz = points[3 * p + 2];
        float ax = 0.0f, ay = 0.0f, az = 0.0f, wsum = 0.0f;
        // w = exp(-d2/(2*sigma^2)) = exp2(d2 * (-1/50 * log2(e)))
        const float kexp = -0.02f * 1.44269504088896340736f;

        #pragma unroll 4
        for (int n = 0; n < NN; ++n) {
            const float4* q = (const float4*)(&nd[n * 16]);
            float4 q0 = q[0];  // R0 R1 R2 R3
            float4 q1 = q[1];  // R4 R5 R6 R7
            float4 q2 = q[2];  // R8 cx cy cz
            float4 q3 = q[3];  // tcx tcy tcz pad
            float dx = px - q2.y, dy = py - q2.z, dz = pz - q2.w;
            float d2 = fmaf(dx, dx, fmaf(dy, dy, dz * dz));
            float w = exp2f(d2 * kexp);
            wsum += w;
            float yx = fmaf(q0.x, dx, fmaf(q0.y, dy, fmaf(q0.z, dz, q3.x)));
            float yy = fmaf(q0.w, dx, fmaf(q1.x, dy, fmaf(q1.y, dz, q3.y)));
            float yz = fmaf(q1.z, dx, fmaf(q1.w, dy, fmaf(q2.x, dz, q3.z)));
            ax = fmaf(w, yx, ax);
            ay = fmaf(w, yy, ay);
            az = fmaf(w, yz, az);
        }
        float invw = 1.0f / (wsum + 1e-5f);
        out[3 * p + 0] = ax * invw;
        out[3 * p + 1] = ay * invw;
        out[3 * p + 2] = az * invw;
    } else {
        // ---- regularizer block (independent of point blocks) ----
        float acc = 0.0f;
        for (int e = tid; e < NE; e += 256) {
            int i = edges[2 * e + 0];
            int j = edges[2 * e + 1];
            float R[9];
            rodrigues(rot[3 * i + 0], rot[3 * i + 1], rot[3 * i + 2], R);
            float cix = cps[3 * i + 0], ciy = cps[3 * i + 1], ciz = cps[3 * i + 2];
            float cjx = cps[3 * j + 0], cjy = cps[3 * j + 1], cjz = cps[3 * j + 2];
            float dx = cjx - cix, dy = cjy - ciy, dz = cjz - ciz;
            float rx = fmaf(R[0], dx, fmaf(R[1], dy, R[2] * dz)) + cix + tr[3 * i + 0] - cjx - tr[3 * j + 0];
            float ry = fmaf(R[3], dx, fmaf(R[4], dy, R[5] * dz)) + ciy + tr[3 * i + 1] - cjy - tr[3 * j + 1];
            float rz = fmaf(R[6], dx, fmaf(R[7], dy, R[8] * dz)) + ciz + tr[3 * i + 2] - cjz - tr[3 * j + 2];
            acc += rx * rx + ry * ry + rz * rz;
        }
        #pragma unroll
        for (int off = 32; off > 0; off >>= 1)
            acc += __shfl_down(acc, off, 64);
        __shared__ float red[4];
        int wid = tid >> 6;
        if ((tid & 63) == 0) red[wid] = acc;
        __syncthreads();
        if (tid == 0) out[3 * NP] = red[0] + red[1] + red[2] + red[3];
    }
}

extern "C" void kernel_launch(void* const* d_in, const int* in_sizes, int n_in,
                              void* d_out, int out_size, void* d_ws, size_t ws_size,
                              hipStream_t stream) {
    const float* points = (const float*)d_in[0];
    const float* cps    = (const float*)d_in[1];
    const float* rot    = (const float*)d_in[2];
    const float* tr     = (const float*)d_in[3];
    const int*   edges  = (const int*)d_in[4];
    float* out = (float*)d_out;
    deform_kernel<<<NP / 256 + 1, 256, 0, stream>>>(points, cps, rot, tr, edges, out);
}

// Round 2
// 89.343 us; speedup vs baseline: 1.1089x; 1.1089x over previous
//
#include <hip/hip_runtime.h>
#include <math.h>

// DeformationGraph: warped[p] = (sum_n w_pn * (R_n p + b_n)) / (sum_n w_pn + 1e-5),
//   b_n = t_n + c_n - R_n c_n,  w_pn = exp2(KEXP*|p-c_n|^2) via dot-identity.
// Plus edge regularizer. P=65536, N=512, E=4096. fp32 VALU-bound.
// Occupancy fix: 1024-thread blocks, 4 node-chunks x 256 points -> 4 waves/SIMD.

constexpr int NP = 65536;
constexpr int NN = 512;
constexpr int NE = 4096;
constexpr int PPB = 256;       // points per block
constexpr int CH = 4;          // node chunks per block (tid>>8)
constexpr int NPC = NN / CH;   // 128 nodes per chunk
constexpr float KEXP = -0.02f * 1.44269504088896340736f;  // -log2(e)/(2*sigma^2)
constexpr float M2K = -2.0f * KEXP;

#if defined(__has_builtin)
#if __has_builtin(__builtin_amdgcn_exp2f)
#define FAST_EXP2(x) __builtin_amdgcn_exp2f(x)
#endif
#endif
#ifndef FAST_EXP2
#define FAST_EXP2(x) exp2f(x)
#endif

__device__ __forceinline__ void rodrigues(float wx, float wy, float wz, float* R) {
    // Matches reference: theta = sqrt(w.w + 1e-12); R = I + sin(th)K + (1-cos(th))K^2
    float t2 = wx * wx + wy * wy + wz * wz + 1e-12f;
    float th = sqrtf(t2);
    float inv = 1.0f / th;
    float kx = wx * inv, ky = wy * inv, kz = wz * inv;
    float s = sinf(th);
    float c = 1.0f - cosf(th);
    float kxky = kx * ky, kxkz = kx * kz, kykz = ky * kz;
    R[0] = 1.0f - c * (ky * ky + kz * kz);
    R[1] = -s * kz + c * kxky;
    R[2] =  s * ky + c * kxkz;
    R[3] =  s * kz + c * kxky;
    R[4] = 1.0f - c * (kx * kx + kz * kz);
    R[5] = -s * kx + c * kykz;
    R[6] = -s * ky + c * kxkz;
    R[7] =  s * kx + c * kykz;
    R[8] = 1.0f - c * (kx * kx + ky * ky);
}

__global__ __launch_bounds__(1024) void deform_kernel(
    const float* __restrict__ points,
    const float* __restrict__ cps,
    const float* __restrict__ rot,
    const float* __restrict__ tr,
    const int* __restrict__ edges,
    float* __restrict__ out)
{
    // Node record (16 floats): R0..R8, bx, by, bz, cx, cy, cz, kc2
    __shared__ float nd[NN * 16];
    __shared__ float4 red[CH - 1][PPB];
    __shared__ float red2[16];

    const int bid = blockIdx.x;
    const int tid = threadIdx.x;

    if (bid < NP / PPB) {
        // ---- stage node table (one Rodrigues per node per block; ~1% overhead) ----
        for (int n = tid; n < NN; n += 1024) {
            float R[9];
            rodrigues(rot[3 * n + 0], rot[3 * n + 1], rot[3 * n + 2], R);
            float cx = cps[3 * n + 0], cy = cps[3 * n + 1], cz = cps[3 * n + 2];
            float tx = tr[3 * n + 0], ty = tr[3 * n + 1], tz = tr[3 * n + 2];
            float bx = tx + cx - (R[0] * cx + R[1] * cy + R[2] * cz);
            float by = ty + cy - (R[3] * cx + R[4] * cy + R[5] * cz);
            float bz = tz + cz - (R[6] * cx + R[7] * cy + R[8] * cz);
            float kc2 = KEXP * (cx * cx + cy * cy + cz * cz);
            float* r = &nd[n * 16];
            r[0] = R[0]; r[1] = R[1]; r[2] = R[2]; r[3] = R[3];
            r[4] = R[4]; r[5] = R[5]; r[6] = R[6]; r[7] = R[7];
            r[8] = R[8]; r[9] = bx;  r[10] = by;  r[11] = bz;
            r[12] = cx;  r[13] = cy; r[14] = cz;  r[15] = kc2;
        }
        __syncthreads();

        // ---- 4 waves of points x 4 node-chunks; fused single pass ----
        const int pt = tid & (PPB - 1);
        const int chunk = tid >> 8;
        const int p = bid * PPB + pt;
        const float px = points[3 * p + 0];
        const float py = points[3 * p + 1];
        const float pz = points[3 * p + 2];
        const float kp2 = KEXP * (px * px + py * py + pz * pz);

        float ax = 0.0f, ay = 0.0f, az = 0.0f, wsum = 0.0f;
        const float* base = &nd[chunk * NPC * 16];

        #pragma unroll 4
        for (int n = 0; n < NPC; ++n) {
            const float4* q = (const float4*)(base + n * 16);
            float4 q0 = q[0];  // R0 R1 R2 R3
            float4 q1 = q[1];  // R4 R5 R6 R7
            float4 q2 = q[2];  // R8 bx by bz
            float4 q3 = q[3];  // cx cy cz kc2
            float dot = fmaf(q3.x, px, fmaf(q3.y, py, q3.z * pz));
            float w = FAST_EXP2(fmaf(M2K, dot, kp2 + q3.w));
            float yx = fmaf(q0.x, px, fmaf(q0.y, py, fmaf(q0.z, pz, q2.y)));
            float yy = fmaf(q0.w, px, fmaf(q1.x, py, fmaf(q1.y, pz, q2.z)));
            float yz = fmaf(q1.z, px, fmaf(q1.w, py, fmaf(q2.x, pz, q2.w)));
            wsum += w;
            ax = fmaf(w, yx, ax);
            ay = fmaf(w, yy, ay);
            az = fmaf(w, yz, az);
        }

        // ---- cross-chunk reduction ----
        if (chunk != 0) {
            red[chunk - 1][pt] = make_float4(ax, ay, az, wsum);
        }
        __syncthreads();
        if (chunk == 0) {
            #pragma unroll
            for (int r = 0; r < CH - 1; ++r) {
                float4 v = red[r][pt];
                ax += v.x; ay += v.y; az += v.z; wsum += v.w;
            }
            float invw = 1.0f / (wsum + 1e-5f);
            out[3 * p + 0] = ax * invw;
            out[3 * p + 1] = ay * invw;
            out[3 * p + 2] = az * invw;
        }
    } else {
        // ---- regularizer block ----
        float acc = 0.0f;
        for (int e = tid; e < NE; e += 1024) {
            int i = edges[2 * e + 0];
            int j = edges[2 * e + 1];
            float R[9];
            rodrigues(rot[3 * i + 0], rot[3 * i + 1], rot[3 * i + 2], R);
            float cix = cps[3 * i + 0], ciy = cps[3 * i + 1], ciz = cps[3 * i + 2];
            float cjx = cps[3 * j + 0], cjy = cps[3 * j + 1], cjz = cps[3 * j + 2];
            float dx = cjx - cix, dy = cjy - ciy, dz = cjz - ciz;
            float rx = fmaf(R[0], dx, fmaf(R[1], dy, R[2] * dz)) + cix + tr[3 * i + 0] - cjx - tr[3 * j + 0];
            float ry = fmaf(R[3], dx, fmaf(R[4], dy, R[5] * dz)) + ciy + tr[3 * i + 1] - cjy - tr[3 * j + 1];
            float rz = fmaf(R[6], dx, fmaf(R[7], dy, R[8] * dz)) + ciz + tr[3 * i + 2] - cjz - tr[3 * j + 2];
            acc += rx * rx + ry * ry + rz * rz;
        }
        #pragma unroll
        for (int off = 32; off > 0; off >>= 1)
            acc += __shfl_down(acc, off, 64);
        int wid = tid >> 6;
        if ((tid & 63) == 0) red2[wid] = acc;
        __syncthreads();
        if (tid == 0) {
            float s = 0.0f;
            #pragma unroll
            for (int i = 0; i < 16; ++i) s += red2[i];
            out[3 * NP] = s;
        }
    }
}

extern "C" void kernel_launch(void* const* d_in, const int* in_sizes, int n_in,
                              void* d_out, int out_size, void* d_ws, size_t ws_size,
                              hipStream_t stream) {
    const float* points = (const float*)d_in[0];
    const float* cps    = (const float*)d_in[1];
    const float* rot    = (const float*)d_in[2];
    const float* tr     = (const float*)d_in[3];
    const int*   edges  = (const int*)d_in[4];
    float* out = (float*)d_out;
    deform_kernel<<<NP / PPB + 1, 1024, 0, stream>>>(points, cps, rot, tr, edges, out);
}

// Round 3
// 85.939 us; speedup vs baseline: 1.1528x; 1.0396x over previous
//
#include <hip/hip_runtime.h>
#include <math.h>

// DeformationGraph: warped[p] = (sum_n w_pn * (R_n p + b_n)) / (sum_n w_pn + 1e-5),
//   b_n = t_n + c_n - R_n c_n,  w_pn = exp2(kp2 + kc2 + M2K*(p.c)) via dot-identity.
// Plus edge regularizer. P=65536, N=512, E=4096.
// Round-3 theory: round-2 was LDS-broadcast-read bound (4 b128/node-iter of
// wave-uniform data ~ 34 us/CU). Fix: 4 points per thread amortizes the same
// node reads over 4x the VALU work -> LDS ~8.5us balanced vs VALU ~8.3us.

constexpr int NP = 65536;
constexpr int NN = 512;
constexpr int NE = 4096;
constexpr int PPT = 4;                 // points per thread
constexpr int CH = 16;                 // node chunks per block
constexpr int TPC = 64;                // threads per chunk (1024/CH)
constexpr int PPB = TPC * PPT;         // 256 points per block
constexpr int NPC = NN / CH;           // 32 nodes per chunk
constexpr float KEXP = -0.02f * 1.44269504088896340736f;  // -log2(e)/(2*sigma^2)
constexpr float M2K = -2.0f * KEXP;

#if defined(__has_builtin)
#if __has_builtin(__builtin_amdgcn_exp2f)
#define FAST_EXP2(x) __builtin_amdgcn_exp2f(x)
#endif
#endif
#ifndef FAST_EXP2
#define FAST_EXP2(x) exp2f(x)
#endif

__device__ __forceinline__ void rodrigues(float wx, float wy, float wz, float* R) {
    // Matches reference: theta = sqrt(w.w + 1e-12); R = I + sin(th)K + (1-cos(th))K^2
    float t2 = wx * wx + wy * wy + wz * wz + 1e-12f;
    float th = sqrtf(t2);
    float inv = 1.0f / th;
    float kx = wx * inv, ky = wy * inv, kz = wz * inv;
    float s = sinf(th);
    float c = 1.0f - cosf(th);
    float kxky = kx * ky, kxkz = kx * kz, kykz = ky * kz;
    R[0] = 1.0f - c * (ky * ky + kz * kz);
    R[1] = -s * kz + c * kxky;
    R[2] =  s * ky + c * kxkz;
    R[3] =  s * kz + c * kxky;
    R[4] = 1.0f - c * (kx * kx + kz * kz);
    R[5] = -s * kx + c * kykz;
    R[6] = -s * ky + c * kxkz;
    R[7] =  s * kx + c * kykz;
    R[8] = 1.0f - c * (kx * kx + ky * ky);
}

__global__ __launch_bounds__(1024) void deform_kernel(
    const float* __restrict__ points,
    const float* __restrict__ cps,
    const float* __restrict__ rot,
    const float* __restrict__ tr,
    const int* __restrict__ edges,
    float* __restrict__ out)
{
    // Node record (16 floats): R0..R8, bx, by, bz, cx, cy, cz, kc2
    __shared__ float nd[NN * 16];
    __shared__ float4 red[CH / 2][PPB];
    __shared__ float red2[16];

    const int bid = blockIdx.x;
    const int tid = threadIdx.x;

    if (bid < NP / PPB) {
        // ---- stage node table (one Rodrigues per node; threads >=512 idle) ----
        if (tid < NN) {
            int n = tid;
            float R[9];
            rodrigues(rot[3 * n + 0], rot[3 * n + 1], rot[3 * n + 2], R);
            float cx = cps[3 * n + 0], cy = cps[3 * n + 1], cz = cps[3 * n + 2];
            float tx = tr[3 * n + 0], ty = tr[3 * n + 1], tz = tr[3 * n + 2];
            float bx = tx + cx - (R[0] * cx + R[1] * cy + R[2] * cz);
            float by = ty + cy - (R[3] * cx + R[4] * cy + R[5] * cz);
            float bz = tz + cz - (R[6] * cx + R[7] * cy + R[8] * cz);
            float kc2 = KEXP * (cx * cx + cy * cy + cz * cz);
            float* r = &nd[n * 16];
            r[0] = R[0]; r[1] = R[1]; r[2] = R[2]; r[3] = R[3];
            r[4] = R[4]; r[5] = R[5]; r[6] = R[6]; r[7] = R[7];
            r[8] = R[8]; r[9] = bx;  r[10] = by;  r[11] = bz;
            r[12] = cx;  r[13] = cy; r[14] = cz;  r[15] = kc2;
        }
        __syncthreads();

        // ---- 16 chunks x 64 threads; each thread = 4 consecutive points ----
        const int chunk = tid >> 6;        // 0..15
        const int tslot = tid & 63;        // 0..63
        const int p0 = bid * PPB + tslot * PPT;

        // coalesced point load: 12 consecutive floats = 3 float4 (16B-aligned)
        const float4* pv = (const float4*)(points + 3 * p0);
        float4 va = pv[0], vb = pv[1], vc = pv[2];
        float px[PPT] = {va.x, va.w, vb.z, vc.y};
        float py[PPT] = {va.y, vb.x, vb.w, vc.z};
        float pz[PPT] = {va.z, vb.y, vc.x, vc.w};
        float kp2[PPT];
        #pragma unroll
        for (int k = 0; k < PPT; ++k)
            kp2[k] = KEXP * (px[k] * px[k] + py[k] * py[k] + pz[k] * pz[k]);

        float ax[PPT] = {0,0,0,0}, ay[PPT] = {0,0,0,0}, az[PPT] = {0,0,0,0}, ws[PPT] = {0,0,0,0};
        const float* base = &nd[chunk * NPC * 16];

        #pragma unroll 2
        for (int n = 0; n < NPC; ++n) {
            const float4* q = (const float4*)(base + n * 16);
            float4 q0 = q[0];  // R0 R1 R2 R3
            float4 q1 = q[1];  // R4 R5 R6 R7
            float4 q2 = q[2];  // R8 bx by bz
            float4 q3 = q[3];  // cx cy cz kc2
            #pragma unroll
            for (int k = 0; k < PPT; ++k) {
                float dot = fmaf(q3.x, px[k], fmaf(q3.y, py[k], q3.z * pz[k]));
                float w = FAST_EXP2(fmaf(M2K, dot, kp2[k] + q3.w));
                float yx = fmaf(q0.x, px[k], fmaf(q0.y, py[k], fmaf(q0.z, pz[k], q2.y)));
                float yy = fmaf(q0.w, px[k], fmaf(q1.x, py[k], fmaf(q1.y, pz[k], q2.z)));
                float yz = fmaf(q1.z, px[k], fmaf(q1.w, py[k], fmaf(q2.x, pz[k], q2.w)));
                ws[k] += w;
                ax[k] = fmaf(w, yx, ax[k]);
                ay[k] = fmaf(w, yy, ay[k]);
                az[k] = fmaf(w, yz, az[k]);
            }
        }

        // ---- log-tree cross-chunk reduction (16 -> 1) ----
        #pragma unroll
        for (int s = CH / 2; s >= 1; s >>= 1) {
            if (chunk >= s && chunk < 2 * s) {
                #pragma unroll
                for (int k = 0; k < PPT; ++k)
                    red[chunk - s][tslot * PPT + k] = make_float4(ax[k], ay[k], az[k], ws[k]);
            }
            __syncthreads();
            if (chunk < s) {
                #pragma unroll
                for (int k = 0; k < PPT; ++k) {
                    float4 v = red[chunk][tslot * PPT + k];
                    ax[k] += v.x; ay[k] += v.y; az[k] += v.z; ws[k] += v.w;
                }
            }
            __syncthreads();
        }

        if (chunk == 0) {
            float o[12];
            #pragma unroll
            for (int k = 0; k < PPT; ++k) {
                float invw = 1.0f / (ws[k] + 1e-5f);
                o[3 * k + 0] = ax[k] * invw;
                o[3 * k + 1] = ay[k] * invw;
                o[3 * k + 2] = az[k] * invw;
            }
            float4* ov = (float4*)(out + 3 * p0);
            ov[0] = make_float4(o[0], o[1], o[2], o[3]);
            ov[1] = make_float4(o[4], o[5], o[6], o[7]);
            ov[2] = make_float4(o[8], o[9], o[10], o[11]);
        }
    } else {
        // ---- regularizer block ----
        float acc = 0.0f;
        for (int e = tid; e < NE; e += 1024) {
            int i = edges[2 * e + 0];
            int j = edges[2 * e + 1];
            float R[9];
            rodrigues(rot[3 * i + 0], rot[3 * i + 1], rot[3 * i + 2], R);
            float cix = cps[3 * i + 0], ciy = cps[3 * i + 1], ciz = cps[3 * i + 2];
            float cjx = cps[3 * j + 0], cjy = cps[3 * j + 1], cjz = cps[3 * j + 2];
            float dx = cjx - cix, dy = cjy - ciy, dz = cjz - ciz;
            float rx = fmaf(R[0], dx, fmaf(R[1], dy, R[2] * dz)) + cix + tr[3 * i + 0] - cjx - tr[3 * j + 0];
            float ry = fmaf(R[3], dx, fmaf(R[4], dy, R[5] * dz)) + ciy + tr[3 * i + 1] - cjy - tr[3 * j + 1];
            float rz = fmaf(R[6], dx, fmaf(R[7], dy, R[8] * dz)) + ciz + tr[3 * i + 2] - cjz - tr[3 * j + 2];
            acc += rx * rx + ry * ry + rz * rz;
        }
        #pragma unroll
        for (int off = 32; off > 0; off >>= 1)
            acc += __shfl_down(acc, off, 64);
        int wid = tid >> 6;
        if ((tid & 63) == 0) red2[wid] = acc;
        __syncthreads();
        if (tid == 0) {
            float s = 0.0f;
            #pragma unroll
            for (int i = 0; i < 16; ++i) s += red2[i];
            out[3 * NP] = s;
        }
    }
}

extern "C" void kernel_launch(void* const* d_in, const int* in_sizes, int n_in,
                              void* d_out, int out_size, void* d_ws, size_t ws_size,
                              hipStream_t stream) {
    const float* points = (const float*)d_in[0];
    const float* cps    = (const float*)d_in[1];
    const float* rot    = (const float*)d_in[2];
    const float* tr     = (const float*)d_in[3];
    const int*   edges  = (const int*)d_in[4];
    float* out = (float*)d_out;
    deform_kernel<<<NP / PPB + 1, 1024, 0, stream>>>(points, cps, rot, tr, edges, out);
}